// Round 1
// baseline (658.830 us; speedup 1.0000x reference)
//
#include <hip/hip_runtime.h>
#include <hip/hip_bf16.h>

#define TOKENS 8192
#define DMODEL 1024
#define NEXP   8
#define DFF    4096
#define CAP    1280

typedef short bf16x8_t __attribute__((ext_vector_type(8)));
typedef float f32x4_t  __attribute__((ext_vector_type(4)));

__device__ __forceinline__ float bf2f(ushort u) {
    union { unsigned int i; float f; } v; v.i = ((unsigned int)u) << 16; return v.f;
}
__device__ __forceinline__ ushort f2bf(float f) {
    union { float f; unsigned int i; } v; v.f = f;
    unsigned int r = v.i + 0x7fffu + ((v.i >> 16) & 1u);   // RNE
    return (ushort)(r >> 16);
}
// async global->LDS DMA, 16B per lane, dest = uniform base + lane*16
__device__ __forceinline__ void load_lds16(const void* g, void* l) {
    __builtin_amdgcn_global_load_lds(
        (const __attribute__((address_space(1))) void*)g,
        (__attribute__((address_space(3))) void*)l, 16, 0, 0);
}

// ---------------------------------------------------------------- gate ------
__global__ __launch_bounds__(256) void gate_kernel(
    const float* __restrict__ tokens, const float* __restrict__ gw,
    int* __restrict__ eidx, float* __restrict__ prob)
{
    int lane = threadIdx.x & 63;
    int wave = threadIdx.x >> 6;
    int t = blockIdx.x * 4 + wave;
    const float* tok = tokens + (long)t * DMODEL;
    float s[NEXP] = {0.f,0.f,0.f,0.f,0.f,0.f,0.f,0.f};
    #pragma unroll
    for (int c = 0; c < 4; c++) {
        int d = c * 256 + lane * 4;
        float4 x = *(const float4*)(tok + d);
        #pragma unroll
        for (int e = 0; e < NEXP; e++) {
            float4 g = *(const float4*)(gw + e * DMODEL + d);
            s[e] += x.x*g.x + x.y*g.y + x.z*g.z + x.w*g.w;
        }
    }
    #pragma unroll
    for (int e = 0; e < NEXP; e++) {
        #pragma unroll
        for (int off = 32; off > 0; off >>= 1) s[e] += __shfl_xor(s[e], off);
    }
    if (lane == 0) {
        float m = s[0]; int am = 0;
        #pragma unroll
        for (int e = 1; e < NEXP; e++) if (s[e] > m) { m = s[e]; am = e; }
        float sum = 0.f;
        #pragma unroll
        for (int e = 0; e < NEXP; e++) sum += expf(s[e] - m);
        eidx[t] = am;
        prob[t] = 1.0f / sum;
    }
}

// ------------------------------------------------------------- routing ------
__global__ __launch_bounds__(256) void route_scan(
    const int* __restrict__ eidx, int* __restrict__ pos)
{
    __shared__ int hist[256][NEXP];
    int tid = threadIdx.x;
    int base = tid * 32;
    #pragma unroll
    for (int e = 0; e < NEXP; e++) hist[tid][e] = 0;
    for (int i = 0; i < 32; i++) hist[tid][eidx[base + i]]++;
    __syncthreads();
    if (tid < NEXP) {
        int run = 0;
        for (int i = 0; i < 256; i++) { int v = hist[i][tid]; hist[i][tid] = run; run += v; }
    }
    __syncthreads();
    for (int i = 0; i < 32; i++) {
        int e = eidx[base + i];
        pos[base + i] = hist[tid][e]++;
    }
}

// ------------------------------------------------------------ dispatch ------
__global__ __launch_bounds__(256) void dispatch_gather(
    const float* __restrict__ tokens, const int* __restrict__ eidx,
    const int* __restrict__ pos, ushort* __restrict__ disp)
{
    int t = blockIdx.x;
    int p = pos[t];
    if (p >= CAP) return;
    int e = eidx[t];
    int d = threadIdx.x * 4;
    float4 v = *(const float4*)(tokens + (long)t * DMODEL + d);
    union { uint2 u; ushort h[4]; } o;
    o.h[0] = f2bf(v.x); o.h[1] = f2bf(v.y); o.h[2] = f2bf(v.z); o.h[3] = f2bf(v.w);
    *(uint2*)(disp + ((long)e * CAP + p) * DMODEL + d) = o.u;
}

// ----------------------------------------------------------- transpose ------
__global__ __launch_bounds__(256) void transpose_f32_bf16(
    const float* __restrict__ in, ushort* __restrict__ out, int R, int C)
{
    __shared__ ushort tile[64][72];
    long base = (long)blockIdx.z * R * C;
    int r0 = blockIdx.y * 64, c0 = blockIdx.x * 64;
    int tid = threadIdx.x;
    int rr = tid >> 2;
    int cc = (tid & 3) * 16;
    const float* ip = in + base + (long)(r0 + rr) * C + (c0 + cc);
    #pragma unroll
    for (int q = 0; q < 4; q++) {
        float4 v = *(const float4*)(ip + q * 4);
        tile[cc + q*4 + 0][rr] = f2bf(v.x);
        tile[cc + q*4 + 1][rr] = f2bf(v.y);
        tile[cc + q*4 + 2][rr] = f2bf(v.z);
        tile[cc + q*4 + 3][rr] = f2bf(v.w);
    }
    __syncthreads();
    ushort* op = out + base + (long)(c0 + rr) * R + (r0 + cc);
    *(uint4*)op       = *(const uint4*)&tile[rr][cc];
    *(uint4*)(op + 8) = *(const uint4*)&tile[rr][cc + 8];
}

// ---------------------------------------------------------------- GEMM ------
// C[M][N] = op(A[M][K] * B[N][K]^T + bias[N]); per-expert via swizzled bz.
// 256x256 tile, BK=64, 8 waves (512 thr), double-buffered LDS (128 KiB).
// 8-phase-style schedule (guide §5 template, T1+T2+T3+T4+T5):
//   - per K-tile: 4 phases, each {ds_reads; [stage]; barrier; setprio(1);
//     16 MFMA; setprio(0); [vmcnt]; barrier}
//   - B-frags (8 ds_read_b128) loaded once per K-tile at phase 0, held in regs
//   - all 8 stage calls (tile t+1) issue at phase 0, order {B0..B3,A0,A2}
//     <fence> {A1,A3}. Waves read A rows 0..63 of their half in phases 0-1
//     and rows 64..127 in phases 2-3, so:
//       phase-1 end: vmcnt(8)  -> retires A1,A3 of CURRENT tile (5-phase-old)
//       phase-3 end: vmcnt(2)  -> retires {B*,A0,A2} of NEXT tile (3-phase-old),
//                                 leaves A1,A3 of next tile in flight (T4).
//     per-wave wait + s_barrier makes the guarantee collective.
// LDS rows = 64 bf16 (8x16B chunks), phys chunk = logical ^ (row&7), applied
// on the global source side so the DMA dest stays base + lane*16 (m104).
#define BM 256
#define BN 256
#define BK 64
#define TILE_E (BM*BK)   // ushorts per buffer per matrix (32 KiB)

__global__ __launch_bounds__(512, 2) void gemm_bt256(
    const ushort* __restrict__ A, const ushort* __restrict__ B,
    const float* __restrict__ bias, ushort* __restrict__ C,
    int N, int K, int do_relu,
    long sA, long sB, long sBias, long sC)
{
    __shared__ ushort As[2*TILE_E];
    __shared__ ushort Bs[2*TILE_E];

    // T1: XCD-aware swizzle (nwg % 8 == 0 guaranteed by launch: 640 / 160)
    int gx = gridDim.x, gy = gridDim.y;
    int nwg = gx * gy * gridDim.z;
    int lin = blockIdx.x + gx * (blockIdx.y + gy * blockIdx.z);
    int cpx = nwg >> 3;
    int swz = (lin & 7) * cpx + (lin >> 3);
    int bz  = swz / (gx * gy);
    int rem = swz - bz * gx * gy;
    int by  = rem / gx, bx = rem - by * gx;

    A += bz * sA; B += bz * sB; bias += bz * sBias; C += bz * sC;
    long m0 = (long)by * BM, n0 = (long)bx * BN;

    int tid  = threadIdx.x;
    int lane = tid & 63, wave = tid >> 6;
    int wm = (wave >> 2) * 128;     // 2 M-groups of 128 rows
    int wn = (wave & 3) * 64;       // 4 N-groups of 64 cols
    int fm = lane & 15;             // fragment row/col within 16
    int q  = lane >> 4;             // 0..3 (k-quad)
    int rx = fm & 7;                // row&7 for read-side swizzle

    // staging: thread covers row rl of each 64-row call group, phys chunk lane&7
    int rl   = wave * 8 + (lane >> 3);
    int loff = ((lane & 7) ^ (lane >> 3)) * 8;       // logical chunk (pre-swizzled src)
    const ushort* Ag = A + (m0 + rl) * (long)K + loff;
    const ushort* Bg = B + (n0 + rl) * (long)K + loff;

    f32x4_t acc[8][4];
    #pragma unroll
    for (int i = 0; i < 8; i++)
        #pragma unroll
        for (int j = 0; j < 4; j++) acc[i][j] = (f32x4_t){0.f,0.f,0.f,0.f};

    int KT = K >> 6;

    // ---- prologue: stage tile 0 into buf 0, drain, barrier (one-time)
    {
        ushort* Ad = As; ushort* Bd = Bs;
        #pragma unroll
        for (int s = 0; s < 4; s++)
            load_lds16(Bg + (long)(64*s) * K, Bd + s*4096 + wave*512);
        load_lds16(Ag,                 Ad + 0*4096 + wave*512);
        load_lds16(Ag + (long)128*K,   Ad + 2*4096 + wave*512);
        load_lds16(Ag + (long) 64*K,   Ad + 1*4096 + wave*512);
        load_lds16(Ag + (long)192*K,   Ad + 3*4096 + wave*512);
        asm volatile("s_waitcnt vmcnt(0)" ::: "memory");
        __builtin_amdgcn_s_barrier();
    }

    for (int kt = 0; kt < KT; ++kt) {
        const ushort* Asb = As + (kt & 1) * TILE_E;
        const ushort* Bsb = Bs + (kt & 1) * TILE_E;
        bf16x8_t bf[4][2];
        #pragma unroll
        for (int ph = 0; ph < 4; ++ph) {
            // ---- ds_reads for this phase
            if (ph == 0) {
                #pragma unroll
                for (int j = 0; j < 4; j++) {
                    int r = wn + 16*j + fm;
                    #pragma unroll
                    for (int kk = 0; kk < 2; kk++)
                        bf[j][kk] = *(const bf16x8_t*)&Bsb[r*64 + (((kk<<2)+q) ^ rx)*8];
                }
            }
            bf16x8_t af[2][2];
            #pragma unroll
            for (int i2 = 0; i2 < 2; i2++) {
                int r = wm + 16*(2*ph + i2) + fm;
                #pragma unroll
                for (int kk = 0; kk < 2; kk++)
                    af[i2][kk] = *(const bf16x8_t*)&Asb[r*64 + (((kk<<2)+q) ^ rx)*8];
            }
            // ---- stage next K-tile (all 8 calls at phase 0)
            if (ph == 0 && kt + 1 < KT) {
                long k0 = (long)(kt + 1) * 64;
                ushort* Ad = As + ((kt + 1) & 1) * TILE_E;
                ushort* Bd = Bs + ((kt + 1) & 1) * TILE_E;
                #pragma unroll
                for (int s = 0; s < 4; s++)
                    load_lds16(Bg + (long)(64*s)*K + k0, Bd + s*4096 + wave*512);
                load_lds16(Ag + k0,                Ad + 0*4096 + wave*512);
                load_lds16(Ag + (long)128*K + k0,  Ad + 2*4096 + wave*512);
                asm volatile("" ::: "memory");          // pin issue order 6 | 2
                __builtin_amdgcn_sched_barrier(0);
                load_lds16(Ag + (long) 64*K + k0,  Ad + 1*4096 + wave*512);
                load_lds16(Ag + (long)192*K + k0,  Ad + 3*4096 + wave*512);
            }
            __builtin_amdgcn_s_barrier();               // pre-MFMA (role split)
            __builtin_amdgcn_s_setprio(1);
            #pragma unroll
            for (int kk = 0; kk < 2; kk++)
                #pragma unroll
                for (int i2 = 0; i2 < 2; i2++)
                    #pragma unroll
                    for (int j = 0; j < 4; j++)
                        acc[2*ph + i2][j] = __builtin_amdgcn_mfma_f32_16x16x32_bf16(
                            af[i2][kk], bf[j][kk], acc[2*ph + i2][j], 0, 0, 0);
            __builtin_amdgcn_s_setprio(0);
            // ---- counted waits (never 0 mid-loop)
            if (ph == 1) {
                if (kt + 1 < KT) asm volatile("s_waitcnt vmcnt(8)" ::: "memory");
                else             asm volatile("s_waitcnt vmcnt(0)" ::: "memory");
            }
            if (ph == 3 && kt + 1 < KT)
                asm volatile("s_waitcnt vmcnt(2)" ::: "memory");
            __builtin_amdgcn_s_barrier();               // phase end
        }
    }

    // epilogue: C/D layout col=lane&15, row=(lane>>4)*4+reg  [m89-verified]
    #pragma unroll
    for (int j = 0; j < 4; j++) {
        long col = n0 + wn + 16*j + fm;
        float bv = bias[col];
        #pragma unroll
        for (int i = 0; i < 8; i++) {
            long row = m0 + wm + 16*i + q * 4;
            #pragma unroll
            for (int r = 0; r < 4; r++) {
                float v = acc[i][j][r] + bv;
                if (do_relu) v = fmaxf(v, 0.f);
                C[(row + r) * N + col] = f2bf(v);
            }
        }
    }
}

// ------------------------------------------------------------- combine ------
__global__ __launch_bounds__(256) void combine_kernel(
    const ushort* __restrict__ eo, const int* __restrict__ eidx,
    const int* __restrict__ pos, const float* __restrict__ prob,
    float* __restrict__ out)
{
    int t = blockIdx.x;
    int p = pos[t];
    int d = threadIdx.x * 4;
    float4 o;
    if (p < CAP) {
        int e = eidx[t];
        float w = prob[t];
        union { uint2 u; ushort h[4]; } v;
        v.u = *(const uint2*)(eo + ((long)e * CAP + p) * DMODEL + d);
        o.x = w * bf2f(v.h[0]);
        o.y = w * bf2f(v.h[1]);
        o.z = w * bf2f(v.h[2]);
        o.w = w * bf2f(v.h[3]);
    } else {
        o = (float4){0.f, 0.f, 0.f, 0.f};
    }
    *(float4*)(out + (long)t * DMODEL + d) = o;
}

// -------------------------------------------------------------- launch ------
extern "C" void kernel_launch(void* const* d_in, const int* in_sizes, int n_in,
                              void* d_out, int out_size, void* d_ws, size_t ws_size,
                              hipStream_t stream) {
    const float* tokens = (const float*)d_in[0];  // [8192][1024] fp32
    const float* gate_w = (const float*)d_in[1];  // [8][1024]
    const float* w1     = (const float*)d_in[2];  // [8][1024][4096]
    const float* b1     = (const float*)d_in[3];  // [8][4096]
    const float* w2     = (const float*)d_in[4];  // [8][4096][1024]
    const float* b2     = (const float*)d_in[5];  // [8][1024]
    float* outp = (float*)d_out;

    char* w = (char*)d_ws;
    ushort* w1T  = (ushort*)w; w += (size_t)NEXP * DFF * DMODEL * 2;   // 67 MB  bf16 [E][DFF][D]
    ushort* w2T  = (ushort*)w; w += (size_t)NEXP * DMODEL * DFF * 2;   // 67 MB  bf16 [E][D][DFF]
    ushort* disp = (ushort*)w; w += (size_t)NEXP * CAP * DMODEL * 2;   // 21 MB  bf16 [E][CAP][D]
    ushort* h    = (ushort*)w; w += (size_t)NEXP * CAP * DFF * 2;      // 84 MB  bf16 [E][CAP][DFF]
    ushort* eo   = (ushort*)w; w += (size_t)NEXP * CAP * DMODEL * 2;   // 21 MB  bf16 [E][CAP][D]
    int*   eidx  = (int*)w;   w += TOKENS * 4;
    int*   pos   = (int*)w;   w += TOKENS * 4;
    float* prob  = (float*)w; w += TOKENS * 4;

    transpose_f32_bf16<<<dim3(DFF/64, DMODEL/64, NEXP), 256, 0, stream>>>(w1, w1T, DMODEL, DFF);
    transpose_f32_bf16<<<dim3(DMODEL/64, DFF/64, NEXP), 256, 0, stream>>>(w2, w2T, DFF, DMODEL);

    gate_kernel<<<TOKENS/4, 256, 0, stream>>>(tokens, gate_w, eidx, prob);
    route_scan<<<1, 256, 0, stream>>>(eidx, pos);
    dispatch_gather<<<TOKENS, 256, 0, stream>>>(tokens, eidx, pos, disp);

    // h = relu(disp @ w1 + b1)   grid 16x5x8 = 640 wg (%8==0)
    gemm_bt256<<<dim3(DFF/BN, CAP/BM, NEXP), 512, 0, stream>>>(
        disp, w1T, b1, h, DFF, DMODEL, 1,
        (long)CAP*DMODEL, (long)DFF*DMODEL, DFF, (long)CAP*DFF);
    // eo = h @ w2 + b2           grid 4x5x8 = 160 wg (%8==0)
    gemm_bt256<<<dim3(DMODEL/BN, CAP/BM, NEXP), 512, 0, stream>>>(
        h, w2T, b2, eo, DMODEL, DFF, 0,
        (long)CAP*DFF, (long)DMODEL*DFF, DMODEL, (long)CAP*DMODEL);

    combine_kernel<<<TOKENS, 256, 0, stream>>>(eo, eidx, pos, prob, outp);
}

// Round 2
// 581.913 us; speedup vs baseline: 1.1322x; 1.1322x over previous
//
#include <hip/hip_runtime.h>
#include <hip/hip_bf16.h>

#define TOKENS 8192
#define DMODEL 1024
#define NEXP   8
#define DFF    4096
#define CAP    1280

typedef short bf16x8_t __attribute__((ext_vector_type(8)));
typedef float f32x4_t  __attribute__((ext_vector_type(4)));

__device__ __forceinline__ float bf2f(ushort u) {
    union { unsigned int i; float f; } v; v.i = ((unsigned int)u) << 16; return v.f;
}
__device__ __forceinline__ ushort f2bf(float f) {
    union { float f; unsigned int i; } v; v.f = f;
    unsigned int r = v.i + 0x7fffu + ((v.i >> 16) & 1u);   // RNE
    return (ushort)(r >> 16);
}
// async global->LDS DMA, 16B per lane, dest = uniform base + lane*16
__device__ __forceinline__ void load_lds16(const void* g, void* l) {
    __builtin_amdgcn_global_load_lds(
        (const __attribute__((address_space(1))) void*)g,
        (__attribute__((address_space(3))) void*)l, 16, 0, 0);
}

// ---------------------------------------------------------------- gate ------
__global__ __launch_bounds__(256) void gate_kernel(
    const float* __restrict__ tokens, const float* __restrict__ gw,
    int* __restrict__ eidx, float* __restrict__ prob)
{
    int lane = threadIdx.x & 63;
    int wave = threadIdx.x >> 6;
    int t = blockIdx.x * 4 + wave;
    const float* tok = tokens + (long)t * DMODEL;
    float s[NEXP] = {0.f,0.f,0.f,0.f,0.f,0.f,0.f,0.f};
    #pragma unroll
    for (int c = 0; c < 4; c++) {
        int d = c * 256 + lane * 4;
        float4 x = *(const float4*)(tok + d);
        #pragma unroll
        for (int e = 0; e < NEXP; e++) {
            float4 g = *(const float4*)(gw + e * DMODEL + d);
            s[e] += x.x*g.x + x.y*g.y + x.z*g.z + x.w*g.w;
        }
    }
    #pragma unroll
    for (int e = 0; e < NEXP; e++) {
        #pragma unroll
        for (int off = 32; off > 0; off >>= 1) s[e] += __shfl_xor(s[e], off);
    }
    if (lane == 0) {
        float m = s[0]; int am = 0;
        #pragma unroll
        for (int e = 1; e < NEXP; e++) if (s[e] > m) { m = s[e]; am = e; }
        float sum = 0.f;
        #pragma unroll
        for (int e = 0; e < NEXP; e++) sum += expf(s[e] - m);
        eidx[t] = am;
        prob[t] = 1.0f / sum;
    }
}

// ------------------------------------------------------------- routing ------
// Deterministic parallel rank: pos[t] = #{t' < t : eidx[t'] == eidx[t]}.
// 1024 threads x 8 tokens. Per-thread 8-expert histogram packed as 2x u64
// (8 x 16-bit fields, totals <= 8192 so no field overflow). Wave shfl-scan
// + cross-wave scan of the packed counters. Replaces the old single-block
// kernel whose 8-thread serial 256-iter scan was ~256 x LDS latency.
__global__ __launch_bounds__(1024) void route_scan(
    const int* __restrict__ eidx, int* __restrict__ pos)
{
    __shared__ unsigned long long pa[16], pb[16];
    int tid = threadIdx.x;
    int lane = tid & 63, wid = tid >> 6;
    int4 e0 = *(const int4*)(eidx + tid * 8);
    int4 e1 = *(const int4*)(eidx + tid * 8 + 4);
    int le[8] = {e0.x, e0.y, e0.z, e0.w, e1.x, e1.y, e1.z, e1.w};
    unsigned long long ha = 0, hb = 0;
    #pragma unroll
    for (int i = 0; i < 8; i++) {
        int e = le[i];
        if (e < 4) ha += 1ull << (e * 16);
        else       hb += 1ull << ((e - 4) * 16);
    }
    unsigned long long ia = ha, ib = hb;       // inclusive scan within wave
    #pragma unroll
    for (int off = 1; off < 64; off <<= 1) {
        unsigned long long ua = __shfl_up(ia, off);
        unsigned long long ub = __shfl_up(ib, off);
        if (lane >= off) { ia += ua; ib += ub; }
    }
    if (lane == 63) { pa[wid] = ia; pb[wid] = ib; }   // wave totals
    __syncthreads();
    if (tid < 64) {   // wave 0 scans the 16 wave totals -> exclusive bases
        unsigned long long va = (lane < 16) ? pa[lane] : 0;
        unsigned long long vb = (lane < 16) ? pb[lane] : 0;
        unsigned long long oa = va, ob = vb;
        #pragma unroll
        for (int off = 1; off < 16; off <<= 1) {
            unsigned long long ua = __shfl_up(va, off);
            unsigned long long ub = __shfl_up(vb, off);
            if (lane >= off) { va += ua; vb += ub; }
        }
        if (lane < 16) { pa[lane] = va - oa; pb[lane] = vb - ob; }
    }
    __syncthreads();
    unsigned long long ba = pa[wid] + (ia - ha);   // exclusive per-thread base
    unsigned long long bb = pb[wid] + (ib - hb);
    int po[8];
    #pragma unroll
    for (int i = 0; i < 8; i++) {
        int e = le[i];
        if (e < 4) { int sh = e * 16;       po[i] = (int)((ba >> sh) & 0xffffu); ba += 1ull << sh; }
        else       { int sh = (e - 4) * 16; po[i] = (int)((bb >> sh) & 0xffffu); bb += 1ull << sh; }
    }
    *(int4*)(pos + tid * 8)     = (int4){po[0], po[1], po[2], po[3]};
    *(int4*)(pos + tid * 8 + 4) = (int4){po[4], po[5], po[6], po[7]};
}

// ------------------------------------------------------------ dispatch ------
__global__ __launch_bounds__(256) void dispatch_gather(
    const float* __restrict__ tokens, const int* __restrict__ eidx,
    const int* __restrict__ pos, ushort* __restrict__ disp)
{
    int t = blockIdx.x;
    int p = pos[t];
    if (p >= CAP) return;
    int e = eidx[t];
    int d = threadIdx.x * 4;
    float4 v = *(const float4*)(tokens + (long)t * DMODEL + d);
    union { uint2 u; ushort h[4]; } o;
    o.h[0] = f2bf(v.x); o.h[1] = f2bf(v.y); o.h[2] = f2bf(v.z); o.h[3] = f2bf(v.w);
    *(uint2*)(disp + ((long)e * CAP + p) * DMODEL + d) = o.u;
}

// ----------------------------------------------------------- transpose ------
// out[c][r] = bf16(in[r][c]) per 64x64 tile.
// Phase 1: full-row coalesced reads (16 lanes x float4 = 256 B segments).
// LDS: flat 64x64 bf16 tile, elem (c,r) at c*64 + ((r>>3)^(c&7))*8 + (r&7)
// (bijective XOR swizzle, keeps 16B alignment for phase-2 ds_read_b128 and
//  spreads the column-scatter stores across banks).
// Phase 2: 8 lanes x uint4 per out row = full 128 B write segments.
__global__ __launch_bounds__(256) void transpose_f32_bf16(
    const float* __restrict__ in, ushort* __restrict__ out, int R, int C)
{
    __shared__ ushort tile[64 * 64];
    long base = (long)blockIdx.z * R * C;
    int r0 = blockIdx.y * 64, c0 = blockIdx.x * 64;
    int tid = threadIdx.x;
    int rr = tid >> 4;            // 0..15
    int cf = (tid & 15) * 4;      // float4 col
    const float* ip = in + base + (long)(r0 + rr) * C + c0 + cf;
    #pragma unroll
    for (int q = 0; q < 4; q++) {
        int r = rr + q * 16;
        float4 v = *(const float4*)(ip + (long)q * 16 * C);
        int rlo = r & 7, rhi = r >> 3;
        tile[(cf+0) * 64 + ((rhi ^ ((cf+0) & 7)) << 3) + rlo] = f2bf(v.x);
        tile[(cf+1) * 64 + ((rhi ^ ((cf+1) & 7)) << 3) + rlo] = f2bf(v.y);
        tile[(cf+2) * 64 + ((rhi ^ ((cf+2) & 7)) << 3) + rlo] = f2bf(v.z);
        tile[(cf+3) * 64 + ((rhi ^ ((cf+3) & 7)) << 3) + rlo] = f2bf(v.w);
    }
    __syncthreads();
    int oc = tid >> 3;            // 0..31
    int j  = tid & 7;             // 16B chunk within out row
    #pragma unroll
    for (int q = 0; q < 2; q++) {
        int c = oc + q * 32;
        uint4 w = *(const uint4*)&tile[c * 64 + ((j ^ (c & 7)) << 3)];
        *(uint4*)(out + base + (long)(c0 + c) * R + r0 + j * 8) = w;
    }
}

// ---------------------------------------------------------------- GEMM ------
// C[M][N] = op(A[M][K] * B[N][K]^T + bias[N]); per-expert via blockIdx.z.
// 128x128 tile, BK=64, 4 waves. m97-style global_load_lds(16B) staging.
// LDS rows are 64 bf16 (128B = 8 chunks of 16B), XOR-swizzled: physical
// chunk p of row r holds logical chunk p ^ (r&7). Swizzle is applied on the
// GLOBAL address side so the DMA dest stays base + lane*16 (m104 constraint).
// Fragment ds_read_b128: 8 lanes per 16B bank-group = b128 conflict floor.
__global__ __launch_bounds__(256) void gemm_bt(
    const ushort* __restrict__ A, const ushort* __restrict__ B,
    const float* __restrict__ bias, ushort* __restrict__ C,
    int M, int N, int K, int do_relu,
    long sA, long sB, long sBias, long sC)
{
    A += blockIdx.z * sA; B += blockIdx.z * sB;
    bias += blockIdx.z * sBias; C += blockIdx.z * sC;

    __shared__ ushort As[128 * 64];   // 16 KB, unpadded (DMA layout)
    __shared__ ushort Bs[128 * 64];

    int tid  = threadIdx.x;
    int lane = tid & 63, wave = tid >> 6;
    int wm = (wave >> 1) * 64, wn = (wave & 1) * 64;
    int fm = lane & 15;             // fragment row/col within 16
    int q  = lane >> 4;             // 0..3  (k-quad)
    int rx = fm & 7;                // row&7 for swizzle on read side
    int m0 = blockIdx.y * 128, n0 = blockIdx.x * 128;

    // staging: lane i covers row (i>>3), swizzled chunk (i&7)^(i>>3)
    int srow = lane >> 3;                       // 0..7 within 8-row group
    int schk = (lane & 7) ^ srow;               // logical chunk to fetch
    const ushort* Ag = A + (long)(m0 + 32*wave + srow) * K + schk * 8;
    const ushort* Bg = B + (long)(n0 + 32*wave + srow) * K + schk * 8;
    ushort* AsW = &As[(32*wave) * 64];          // wave-uniform LDS bases
    ushort* BsW = &Bs[(32*wave) * 64];

    f32x4_t acc[4][4];
    #pragma unroll
    for (int i = 0; i < 4; i++)
        #pragma unroll
        for (int j = 0; j < 4; j++) acc[i][j] = (f32x4_t){0.f,0.f,0.f,0.f};

    for (int k0 = 0; k0 < K; k0 += 64) {
        #pragma unroll
        for (int t = 0; t < 4; t++) {
            load_lds16(Ag + (long)(8*t) * K + k0, AsW + (8*t) * 64);
            load_lds16(Bg + (long)(8*t) * K + k0, BsW + (8*t) * 64);
        }
        __syncthreads();   // compiler drains vmcnt before s_barrier
        #pragma unroll
        for (int kk = 0; kk < 64; kk += 32) {
            int l0 = (kk >> 3) + q;             // logical chunk for this frag
            bf16x8_t af[4], bf[4];
            #pragma unroll
            for (int i = 0; i < 4; i++) {
                int r = wm + 16*i + fm;
                af[i] = *(const bf16x8_t*)&As[r * 64 + (l0 ^ rx) * 8];
            }
            #pragma unroll
            for (int j = 0; j < 4; j++) {
                int r = wn + 16*j + fm;
                bf[j] = *(const bf16x8_t*)&Bs[r * 64 + (l0 ^ rx) * 8];
            }
            #pragma unroll
            for (int i = 0; i < 4; i++)
                #pragma unroll
                for (int j = 0; j < 4; j++)
                    acc[i][j] = __builtin_amdgcn_mfma_f32_16x16x32_bf16(af[i], bf[j], acc[i][j], 0, 0, 0);
        }
        __syncthreads();   // all reads done before next tile's DMA overwrites
    }

    // epilogue: C/D layout col=lane&15, row=(lane>>4)*4+reg  [m89-verified]
    #pragma unroll
    for (int j = 0; j < 4; j++) {
        int col = n0 + wn + 16*j + fm;
        float bv = bias[col];
        #pragma unroll
        for (int i = 0; i < 4; i++) {
            int row = m0 + wm + 16*i + q * 4;
            #pragma unroll
            for (int r = 0; r < 4; r++) {
                float v = acc[i][j][r] + bv;
                if (do_relu) v = fmaxf(v, 0.f);
                C[(long)(row + r) * N + col] = f2bf(v);
            }
        }
    }
}

// ------------------------------------------------------------- combine ------
__global__ __launch_bounds__(256) void combine_kernel(
    const ushort* __restrict__ eo, const int* __restrict__ eidx,
    const int* __restrict__ pos, const float* __restrict__ prob,
    float* __restrict__ out)
{
    int t = blockIdx.x;
    int p = pos[t];
    int d = threadIdx.x * 4;
    float4 o;
    if (p < CAP) {
        int e = eidx[t];
        float w = prob[t];
        union { uint2 u; ushort h[4]; } v;
        v.u = *(const uint2*)(eo + ((long)e * CAP + p) * DMODEL + d);
        o.x = w * bf2f(v.h[0]);
        o.y = w * bf2f(v.h[1]);
        o.z = w * bf2f(v.h[2]);
        o.w = w * bf2f(v.h[3]);
    } else {
        o = (float4){0.f, 0.f, 0.f, 0.f};
    }
    *(float4*)(out + (long)t * DMODEL + d) = o;
}

// -------------------------------------------------------------- launch ------
extern "C" void kernel_launch(void* const* d_in, const int* in_sizes, int n_in,
                              void* d_out, int out_size, void* d_ws, size_t ws_size,
                              hipStream_t stream) {
    const float* tokens = (const float*)d_in[0];  // [8192][1024] fp32
    const float* gate_w = (const float*)d_in[1];  // [8][1024]
    const float* w1     = (const float*)d_in[2];  // [8][1024][4096]
    const float* b1     = (const float*)d_in[3];  // [8][4096]
    const float* w2     = (const float*)d_in[4];  // [8][4096][1024]
    const float* b2     = (const float*)d_in[5];  // [8][1024]
    float* outp = (float*)d_out;

    char* w = (char*)d_ws;
    ushort* w1T  = (ushort*)w; w += (size_t)NEXP * DFF * DMODEL * 2;   // 67 MB  bf16 [E][DFF][D]
    ushort* w2T  = (ushort*)w; w += (size_t)NEXP * DMODEL * DFF * 2;   // 67 MB  bf16 [E][D][DFF]
    ushort* disp = (ushort*)w; w += (size_t)NEXP * CAP * DMODEL * 2;   // 21 MB  bf16 [E][CAP][D]
    ushort* h    = (ushort*)w; w += (size_t)NEXP * CAP * DFF * 2;      // 84 MB  bf16 [E][CAP][DFF]
    ushort* eo   = (ushort*)w; w += (size_t)NEXP * CAP * DMODEL * 2;   // 21 MB  bf16 [E][CAP][D]
    int*   eidx  = (int*)w;   w += TOKENS * 4;
    int*   pos   = (int*)w;   w += TOKENS * 4;
    float* prob  = (float*)w; w += TOKENS * 4;

    transpose_f32_bf16<<<dim3(DFF/64, DMODEL/64, NEXP), 256, 0, stream>>>(w1, w1T, DMODEL, DFF);
    transpose_f32_bf16<<<dim3(DMODEL/64, DFF/64, NEXP), 256, 0, stream>>>(w2, w2T, DFF, DMODEL);

    gate_kernel<<<TOKENS/4, 256, 0, stream>>>(tokens, gate_w, eidx, prob);
    route_scan<<<1, 1024, 0, stream>>>(eidx, pos);
    dispatch_gather<<<TOKENS, 256, 0, stream>>>(tokens, eidx, pos, disp);

    // h = relu(disp @ w1 + b1)
    gemm_bt<<<dim3(DFF/128, CAP/128, NEXP), 256, 0, stream>>>(
        disp, w1T, b1, h, CAP, DFF, DMODEL, 1,
        (long)CAP*DMODEL, (long)DFF*DMODEL, DFF, (long)CAP*DFF);
    // eo = h @ w2 + b2
    gemm_bt<<<dim3(DMODEL/128, CAP/128, NEXP), 256, 0, stream>>>(
        h, w2T, b2, eo, CAP, DMODEL, DFF, 0,
        (long)CAP*DFF, (long)DMODEL*DFF, DMODEL, (long)CAP*DMODEL);

    combine_kernel<<<TOKENS, 256, 0, stream>>>(eo, eidx, pos, prob, outp);
}

// Round 3
// 563.208 us; speedup vs baseline: 1.1698x; 1.0332x over previous
//
#include <hip/hip_runtime.h>
#include <hip/hip_bf16.h>

#define TOKENS 8192
#define DMODEL 1024
#define NEXP   8
#define DFF    4096
#define CAP    1280

typedef short bf16x8_t __attribute__((ext_vector_type(8)));
typedef float f32x4_t  __attribute__((ext_vector_type(4)));

__device__ __forceinline__ float bf2f(ushort u) {
    union { unsigned int i; float f; } v; v.i = ((unsigned int)u) << 16; return v.f;
}
__device__ __forceinline__ ushort f2bf(float f) {
    union { float f; unsigned int i; } v; v.f = f;
    unsigned int r = v.i + 0x7fffu + ((v.i >> 16) & 1u);   // RNE
    return (ushort)(r >> 16);
}
// async global->LDS DMA, 16B per lane, dest = uniform base + lane*16
__device__ __forceinline__ void load_lds16(const void* g, void* l) {
    __builtin_amdgcn_global_load_lds(
        (const __attribute__((address_space(1))) void*)g,
        (__attribute__((address_space(3))) void*)l, 16, 0, 0);
}

// ---------------------------------------------------------------- gate ------
__global__ __launch_bounds__(256) void gate_kernel(
    const float* __restrict__ tokens, const float* __restrict__ gw,
    int* __restrict__ eidx, float* __restrict__ prob)
{
    int lane = threadIdx.x & 63;
    int wave = threadIdx.x >> 6;
    int t = blockIdx.x * 4 + wave;
    const float* tok = tokens + (long)t * DMODEL;
    float s[NEXP] = {0.f,0.f,0.f,0.f,0.f,0.f,0.f,0.f};
    #pragma unroll
    for (int c = 0; c < 4; c++) {
        int d = c * 256 + lane * 4;
        float4 x = *(const float4*)(tok + d);
        #pragma unroll
        for (int e = 0; e < NEXP; e++) {
            float4 g = *(const float4*)(gw + e * DMODEL + d);
            s[e] += x.x*g.x + x.y*g.y + x.z*g.z + x.w*g.w;
        }
    }
    #pragma unroll
    for (int e = 0; e < NEXP; e++) {
        #pragma unroll
        for (int off = 32; off > 0; off >>= 1) s[e] += __shfl_xor(s[e], off);
    }
    if (lane == 0) {
        float m = s[0]; int am = 0;
        #pragma unroll
        for (int e = 1; e < NEXP; e++) if (s[e] > m) { m = s[e]; am = e; }
        float sum = 0.f;
        #pragma unroll
        for (int e = 0; e < NEXP; e++) sum += expf(s[e] - m);
        eidx[t] = am;
        prob[t] = 1.0f / sum;
    }
}

// ------------------------------------------------------------- routing ------
// Deterministic parallel rank: pos[t] = #{t' < t : eidx[t'] == eidx[t]}.
// 1024 threads x 8 tokens. Per-thread 8-expert histogram packed as 2x u64
// (8 x 16-bit fields, totals <= 8192 so no field overflow). Wave shfl-scan
// + cross-wave scan of the packed counters. Also exports per-expert totals
// cnt[8] (free: lane 15 of the cross-wave inclusive scan holds them) so the
// GEMMs can skip M-blocks beyond each expert's actual token count.
__global__ __launch_bounds__(1024) void route_scan(
    const int* __restrict__ eidx, int* __restrict__ pos, int* __restrict__ cnt)
{
    __shared__ unsigned long long pa[16], pb[16];
    int tid = threadIdx.x;
    int lane = tid & 63, wid = tid >> 6;
    int4 e0 = *(const int4*)(eidx + tid * 8);
    int4 e1 = *(const int4*)(eidx + tid * 8 + 4);
    int le[8] = {e0.x, e0.y, e0.z, e0.w, e1.x, e1.y, e1.z, e1.w};
    unsigned long long ha = 0, hb = 0;
    #pragma unroll
    for (int i = 0; i < 8; i++) {
        int e = le[i];
        if (e < 4) ha += 1ull << (e * 16);
        else       hb += 1ull << ((e - 4) * 16);
    }
    unsigned long long ia = ha, ib = hb;       // inclusive scan within wave
    #pragma unroll
    for (int off = 1; off < 64; off <<= 1) {
        unsigned long long ua = __shfl_up(ia, off);
        unsigned long long ub = __shfl_up(ib, off);
        if (lane >= off) { ia += ua; ib += ub; }
    }
    if (lane == 63) { pa[wid] = ia; pb[wid] = ib; }   // wave totals
    __syncthreads();
    if (tid < 64) {   // wave 0 scans the 16 wave totals -> exclusive bases
        unsigned long long va = (lane < 16) ? pa[lane] : 0;
        unsigned long long vb = (lane < 16) ? pb[lane] : 0;
        unsigned long long oa = va, ob = vb;
        #pragma unroll
        for (int off = 1; off < 16; off <<= 1) {
            unsigned long long ua = __shfl_up(va, off);
            unsigned long long ub = __shfl_up(vb, off);
            if (lane >= off) { va += ua; vb += ub; }
        }
        if (lane < 16) { pa[lane] = va - oa; pb[lane] = vb - ob; }
        if (lane == 15) {   // inclusive over all 16 waves = per-expert totals
            #pragma unroll
            for (int e = 0; e < 4; e++) {
                cnt[e]     = (int)((va >> (e * 16)) & 0xffffu);
                cnt[e + 4] = (int)((vb >> (e * 16)) & 0xffffu);
            }
        }
    }
    __syncthreads();
    unsigned long long ba = pa[wid] + (ia - ha);   // exclusive per-thread base
    unsigned long long bb = pb[wid] + (ib - hb);
    int po[8];
    #pragma unroll
    for (int i = 0; i < 8; i++) {
        int e = le[i];
        if (e < 4) { int sh = e * 16;       po[i] = (int)((ba >> sh) & 0xffffu); ba += 1ull << sh; }
        else       { int sh = (e - 4) * 16; po[i] = (int)((bb >> sh) & 0xffffu); bb += 1ull << sh; }
    }
    *(int4*)(pos + tid * 8)     = (int4){po[0], po[1], po[2], po[3]};
    *(int4*)(pos + tid * 8 + 4) = (int4){po[4], po[5], po[6], po[7]};
}

// ------------------------------------------------------------ dispatch ------
__global__ __launch_bounds__(256) void dispatch_gather(
    const float* __restrict__ tokens, const int* __restrict__ eidx,
    const int* __restrict__ pos, ushort* __restrict__ disp)
{
    int t = blockIdx.x;
    int p = pos[t];
    if (p >= CAP) return;
    int e = eidx[t];
    int d = threadIdx.x * 4;
    float4 v = *(const float4*)(tokens + (long)t * DMODEL + d);
    union { uint2 u; ushort h[4]; } o;
    o.h[0] = f2bf(v.x); o.h[1] = f2bf(v.y); o.h[2] = f2bf(v.z); o.h[3] = f2bf(v.w);
    *(uint2*)(disp + ((long)e * CAP + p) * DMODEL + d) = o.u;
}

// ----------------------------------------------------------- transpose ------
// out[c][r] = bf16(in[r][c]) per 64x64 tile.
// Phase 1: full-row coalesced reads (16 lanes x float4 = 256 B segments).
// LDS: flat 64x64 bf16 tile, elem (c,r) at c*64 + ((r>>3)^(c&7))*8 + (r&7)
// (bijective XOR swizzle, keeps 16B alignment for phase-2 ds_read_b128).
// Phase 2: 8 lanes x uint4 per out row = full 128 B write segments.
__global__ __launch_bounds__(256) void transpose_f32_bf16(
    const float* __restrict__ in, ushort* __restrict__ out, int R, int C)
{
    __shared__ ushort tile[64 * 64];
    long base = (long)blockIdx.z * R * C;
    int r0 = blockIdx.y * 64, c0 = blockIdx.x * 64;
    int tid = threadIdx.x;
    int rr = tid >> 4;            // 0..15
    int cf = (tid & 15) * 4;      // float4 col
    const float* ip = in + base + (long)(r0 + rr) * C + c0 + cf;
    #pragma unroll
    for (int q = 0; q < 4; q++) {
        int r = rr + q * 16;
        float4 v = *(const float4*)(ip + (long)q * 16 * C);
        int rlo = r & 7, rhi = r >> 3;
        tile[(cf+0) * 64 + ((rhi ^ ((cf+0) & 7)) << 3) + rlo] = f2bf(v.x);
        tile[(cf+1) * 64 + ((rhi ^ ((cf+1) & 7)) << 3) + rlo] = f2bf(v.y);
        tile[(cf+2) * 64 + ((rhi ^ ((cf+2) & 7)) << 3) + rlo] = f2bf(v.z);
        tile[(cf+3) * 64 + ((rhi ^ ((cf+3) & 7)) << 3) + rlo] = f2bf(v.w);
    }
    __syncthreads();
    int oc = tid >> 3;            // 0..31
    int j  = tid & 7;             // 16B chunk within out row
    #pragma unroll
    for (int q = 0; q < 2; q++) {
        int c = oc + q * 32;
        uint4 w = *(const uint4*)&tile[c * 64 + ((j ^ (c & 7)) << 3)];
        *(uint4*)(out + base + (long)(c0 + c) * R + r0 + j * 8) = w;
    }
}

// ---------------------------------------------------------------- GEMM ------
// C[M][N] = op(A[M][K] * B[N][K]^T + bias[N]); per-expert via blockIdx.z.
// 128x128 tile, BK=64, 4 waves. m97-style global_load_lds(16B) staging.
// LDS rows are 64 bf16 (128B = 8 chunks of 16B), XOR-swizzled: physical
// chunk p of row r holds logical chunk p ^ (r&7). Swizzle is applied on the
// GLOBAL address side so the DMA dest stays base + lane*16 (m104 constraint).
// Fragment ds_read_b128: 8 lanes per 16B bank-group = b128 conflict floor.
// MoE capacity skip: M-blocks whose row range lies beyond the expert's
// actual token count do no useful work (rows never written by dispatch /
// never read by combine) -> early-out. Rows are independent, so partial
// blocks computing garbage rows are harmless.
__global__ __launch_bounds__(256) void gemm_bt(
    const ushort* __restrict__ A, const ushort* __restrict__ B,
    const float* __restrict__ bias, ushort* __restrict__ C,
    const int* __restrict__ cnt,
    int M, int N, int K, int do_relu,
    long sA, long sB, long sBias, long sC)
{
    if ((int)blockIdx.y * 128 >= cnt[blockIdx.z]) return;   // capacity slack

    A += blockIdx.z * sA; B += blockIdx.z * sB;
    bias += blockIdx.z * sBias; C += blockIdx.z * sC;

    __shared__ ushort As[128 * 64];   // 16 KB, unpadded (DMA layout)
    __shared__ ushort Bs[128 * 64];

    int tid  = threadIdx.x;
    int lane = tid & 63, wave = tid >> 6;
    int wm = (wave >> 1) * 64, wn = (wave & 1) * 64;
    int fm = lane & 15;             // fragment row/col within 16
    int q  = lane >> 4;             // 0..3  (k-quad)
    int rx = fm & 7;                // row&7 for swizzle on read side
    int m0 = blockIdx.y * 128, n0 = blockIdx.x * 128;

    // staging: lane i covers row (i>>3), swizzled chunk (i&7)^(i>>3)
    int srow = lane >> 3;                       // 0..7 within 8-row group
    int schk = (lane & 7) ^ srow;               // logical chunk to fetch
    const ushort* Ag = A + (long)(m0 + 32*wave + srow) * K + schk * 8;
    const ushort* Bg = B + (long)(n0 + 32*wave + srow) * K + schk * 8;
    ushort* AsW = &As[(32*wave) * 64];          // wave-uniform LDS bases
    ushort* BsW = &Bs[(32*wave) * 64];

    f32x4_t acc[4][4];
    #pragma unroll
    for (int i = 0; i < 4; i++)
        #pragma unroll
        for (int j = 0; j < 4; j++) acc[i][j] = (f32x4_t){0.f,0.f,0.f,0.f};

    for (int k0 = 0; k0 < K; k0 += 64) {
        #pragma unroll
        for (int t = 0; t < 4; t++) {
            load_lds16(Ag + (long)(8*t) * K + k0, AsW + (8*t) * 64);
            load_lds16(Bg + (long)(8*t) * K + k0, BsW + (8*t) * 64);
        }
        __syncthreads();   // compiler drains vmcnt before s_barrier
        #pragma unroll
        for (int kk = 0; kk < 64; kk += 32) {
            int l0 = (kk >> 3) + q;             // logical chunk for this frag
            bf16x8_t af[4], bf[4];
            #pragma unroll
            for (int i = 0; i < 4; i++) {
                int r = wm + 16*i + fm;
                af[i] = *(const bf16x8_t*)&As[r * 64 + (l0 ^ rx) * 8];
            }
            #pragma unroll
            for (int j = 0; j < 4; j++) {
                int r = wn + 16*j + fm;
                bf[j] = *(const bf16x8_t*)&Bs[r * 64 + (l0 ^ rx) * 8];
            }
            #pragma unroll
            for (int i = 0; i < 4; i++)
                #pragma unroll
                for (int j = 0; j < 4; j++)
                    acc[i][j] = __builtin_amdgcn_mfma_f32_16x16x32_bf16(af[i], bf[j], acc[i][j], 0, 0, 0);
        }
        __syncthreads();   // all reads done before next tile's DMA overwrites
    }

    // epilogue: C/D layout col=lane&15, row=(lane>>4)*4+reg  [m89-verified]
    #pragma unroll
    for (int j = 0; j < 4; j++) {
        int col = n0 + wn + 16*j + fm;
        float bv = bias[col];
        #pragma unroll
        for (int i = 0; i < 4; i++) {
            int row = m0 + wm + 16*i + q * 4;
            #pragma unroll
            for (int r = 0; r < 4; r++) {
                float v = acc[i][j][r] + bv;
                if (do_relu) v = fmaxf(v, 0.f);
                C[(long)(row + r) * N + col] = f2bf(v);
            }
        }
    }
}

// ------------------------------------------------------------- combine ------
__global__ __launch_bounds__(256) void combine_kernel(
    const ushort* __restrict__ eo, const int* __restrict__ eidx,
    const int* __restrict__ pos, const float* __restrict__ prob,
    float* __restrict__ out)
{
    int t = blockIdx.x;
    int p = pos[t];
    int d = threadIdx.x * 4;
    float4 o;
    if (p < CAP) {
        int e = eidx[t];
        float w = prob[t];
        union { uint2 u; ushort h[4]; } v;
        v.u = *(const uint2*)(eo + ((long)e * CAP + p) * DMODEL + d);
        o.x = w * bf2f(v.h[0]);
        o.y = w * bf2f(v.h[1]);
        o.z = w * bf2f(v.h[2]);
        o.w = w * bf2f(v.h[3]);
    } else {
        o = (float4){0.f, 0.f, 0.f, 0.f};
    }
    *(float4*)(out + (long)t * DMODEL + d) = o;
}

// -------------------------------------------------------------- launch ------
extern "C" void kernel_launch(void* const* d_in, const int* in_sizes, int n_in,
                              void* d_out, int out_size, void* d_ws, size_t ws_size,
                              hipStream_t stream) {
    const float* tokens = (const float*)d_in[0];  // [8192][1024] fp32
    const float* gate_w = (const float*)d_in[1];  // [8][1024]
    const float* w1     = (const float*)d_in[2];  // [8][1024][4096]
    const float* b1     = (const float*)d_in[3];  // [8][4096]
    const float* w2     = (const float*)d_in[4];  // [8][4096][1024]
    const float* b2     = (const float*)d_in[5];  // [8][1024]
    float* outp = (float*)d_out;

    char* w = (char*)d_ws;
    ushort* w1T  = (ushort*)w; w += (size_t)NEXP * DFF * DMODEL * 2;   // 67 MB  bf16 [E][DFF][D]
    ushort* w2T  = (ushort*)w; w += (size_t)NEXP * DMODEL * DFF * 2;   // 67 MB  bf16 [E][D][DFF]
    ushort* disp = (ushort*)w; w += (size_t)NEXP * CAP * DMODEL * 2;   // 21 MB  bf16 [E][CAP][D]
    ushort* h    = (ushort*)w; w += (size_t)NEXP * CAP * DFF * 2;      // 84 MB  bf16 [E][CAP][DFF]
    ushort* eo   = (ushort*)w; w += (size_t)NEXP * CAP * DMODEL * 2;   // 21 MB  bf16 [E][CAP][D]
    int*   eidx  = (int*)w;   w += TOKENS * 4;
    int*   pos   = (int*)w;   w += TOKENS * 4;
    float* prob  = (float*)w; w += TOKENS * 4;
    int*   cnt   = (int*)w;   w += NEXP * 4;

    transpose_f32_bf16<<<dim3(DFF/64, DMODEL/64, NEXP), 256, 0, stream>>>(w1, w1T, DMODEL, DFF);
    transpose_f32_bf16<<<dim3(DMODEL/64, DFF/64, NEXP), 256, 0, stream>>>(w2, w2T, DFF, DMODEL);

    gate_kernel<<<TOKENS/4, 256, 0, stream>>>(tokens, gate_w, eidx, prob);
    route_scan<<<1, 1024, 0, stream>>>(eidx, pos, cnt);
    dispatch_gather<<<TOKENS, 256, 0, stream>>>(tokens, eidx, pos, disp);

    // h = relu(disp @ w1 + b1)
    gemm_bt<<<dim3(DFF/128, CAP/128, NEXP), 256, 0, stream>>>(
        disp, w1T, b1, h, cnt, CAP, DFF, DMODEL, 1,
        (long)CAP*DMODEL, (long)DFF*DMODEL, DFF, (long)CAP*DFF);
    // eo = h @ w2 + b2
    gemm_bt<<<dim3(DMODEL/128, CAP/128, NEXP), 256, 0, stream>>>(
        h, w2T, b2, eo, cnt, CAP, DMODEL, DFF, 0,
        (long)CAP*DFF, (long)DMODEL*DFF, DMODEL, (long)CAP*DMODEL);

    combine_kernel<<<TOKENS, 256, 0, stream>>>(eo, eidx, pos, prob, outp);
}